// Round 1
// baseline (89.950 us; speedup 1.0000x reference)
//
#include <hip/hip_runtime.h>
#include <hip/hip_bf16.h>
#include <math.h>

// Problem constants (from reference):
//   B=16, N_CTX=1024, N_X=N_Y=64, grid g = iy*64+ix,
//   xs[ix] = -10 + 20*ix/63,  ys[iy] = 10 - 20*iy/63
//   out[b,c,iy,ix], c in {dens, FM1/dens, FM2/dens}
#define NB    16
#define NCTX  1024
#define NXG   64
#define NG    4096   // 64*64
#define GT_PER_B 16  // 4096 / 256

__global__ __launch_bounds__(256)
void equiv_encoder_kernel(const float* __restrict__ X,
                          const float* __restrict__ Y,
                          const float* __restrict__ log_l_scale,
                          float* __restrict__ out) {
    const int b  = blockIdx.x >> 4;        // 16 g-tiles per batch
    const int gt = blockIdx.x & 15;
    const int g  = gt * 256 + threadIdx.x; // grid cell 0..4095
    const int ix = g & 63;
    const int iy = g >> 6;

    const float step = 20.0f / 63.0f;
    const float gx = -10.0f + step * (float)ix;   // xs[ix]
    const float gy =  10.0f - step * (float)iy;   // ys[iy]

    // exp(-0.5*d2/l^2) = exp2(d2 * scale), scale = -0.5*log2(e)*exp(-2*logl)
    const float logl  = log_l_scale[0];
    const float scale = -0.72134752044448170f * expf(-2.0f * logl);

    // Stage X (2 floats) and Y (2 floats) per context point, interleaved.
    __shared__ float4 s[NCTX];  // 16 KB
    const float2* Xb = (const float2*)(X + (size_t)b * NCTX * 2);
    const float2* Yb = (const float2*)(Y + (size_t)b * NCTX * 2);
    for (int i = threadIdx.x; i < NCTX; i += 256) {
        float2 xv = Xb[i];
        float2 yv = Yb[i];
        s[i] = make_float4(xv.x, xv.y, yv.x, yv.y);
    }
    __syncthreads();

    float a0 = 0.0f, a1 = 0.0f, a2 = 0.0f;
#pragma unroll 8
    for (int n = 0; n < NCTX; ++n) {
        float4 v = s[n];                 // broadcast ds_read_b128
        float dx = gx - v.x;
        float dy = gy - v.y;
        float d2 = fmaf(dx, dx, dy * dy);
        float w  = exp2f(d2 * scale);    // v_exp_f32
        a0 += w;
        a1 = fmaf(w, v.z, a1);
        a2 = fmaf(w, v.w, a2);
    }

    const float inv = 1.0f / a0;         // a0 > 0 (sum of exps)
    float* ob = out + (size_t)b * 3 * NG;
    ob[g]            = a0;
    ob[NG + g]       = a1 * inv;
    ob[2 * NG + g]   = a2 * inv;
}

extern "C" void kernel_launch(void* const* d_in, const int* in_sizes, int n_in,
                              void* d_out, int out_size, void* d_ws, size_t ws_size,
                              hipStream_t stream) {
    const float* X    = (const float*)d_in[0];   // (16,1024,2) fp32
    const float* Y    = (const float*)d_in[1];   // (16,1024,2) fp32
    const float* logl = (const float*)d_in[2];   // scalar fp32
    float* out = (float*)d_out;                  // (16,3,64,64) fp32

    dim3 grid(NB * GT_PER_B);  // 256 blocks
    dim3 block(256);
    equiv_encoder_kernel<<<grid, block, 0, stream>>>(X, Y, logl, out);
}

// Round 2
// 72.900 us; speedup vs baseline: 1.2339x; 1.2339x over previous
//
#include <hip/hip_runtime.h>
#include <hip/hip_bf16.h>
#include <math.h>

// EquivEncoder: B=16, N_CTX=1024, 64x64 grid.
// out[b,c,iy,ix]: c0 = dens = sum_n w, c1 = (sum_n w*y0)/dens, c2 = (sum_n w*y1)/dens
// w = exp(-0.5*d2/l^2) = exp2(s*dx^2)*exp2(s*dy^2), s = -0.5*log2(e)*exp(-2*logl)
//
// R2 design:
//  - separable exp: LDS tables wx[n][ix], wy[n][iy]  (cuts 67M exps -> 2M)
//  - n-split 16 ways across blocks for TLP (R1 had 1 wave/SIMD, VALUBusy 54%)
//  - kernel1: 1024 blocks = (b:16, gq:4 iy-quarters, nc:16 n-chunks), 256 thr,
//    2x2 register tile/thread, partials -> d_ws (12.6 MB)
//  - kernel2: sum 16 partials + divide -> out

#define NB     16
#define NCTX   1024
#define NG     4096
#define NC     64      // n-chunk size
#define NSPLIT 16      // NCTX / NC
#define GQ     4       // iy quarters (16 iy-rows per block)

__global__ __launch_bounds__(256)
void ee_partial(const float* __restrict__ X,
                const float* __restrict__ Y,
                const float* __restrict__ log_l_scale,
                float* __restrict__ ws) {
    const int blk = blockIdx.x;
    const int b   = blk >> 6;          // GQ*NSPLIT = 64 blocks per batch
    const int r   = blk & 63;
    const int gq  = r >> 4;            // 0..3
    const int nc  = r & 15;            // 0..15
    const int n0  = nc * NC;
    const int iy0 = gq * 16;

    const float step  = 20.0f / 63.0f;
    const float scale = -0.72134752044448170f * expf(-2.0f * log_l_scale[0]);

    __shared__ float  wx[NC][64];   // 16 KB: exp2(s*dx^2) per (n, ix)
    __shared__ float  wy[NC][16];   // 4 KB:  exp2(s*dy^2) per (n, iy-local)
    __shared__ float2 sy[NC];       // 512 B: (y0, y1)

    const float2* Xb = (const float2*)(X + (size_t)b * NCTX * 2);
    const float2* Yb = (const float2*)(Y + (size_t)b * NCTX * 2);

    // --- precompute tables (per-thread exps: 16 + 4) ---
    for (int idx = threadIdx.x; idx < NC * 64; idx += 256) {
        const int j = idx >> 6, i = idx & 63;
        const float dx = (-10.0f + step * (float)i) - Xb[n0 + j].x;
        wx[j][i] = exp2f(dx * dx * scale);
    }
    for (int idx = threadIdx.x; idx < NC * 16; idx += 256) {
        const int j = idx >> 4, q = idx & 15;
        const float dy = (10.0f - step * (float)(iy0 + q)) - Xb[n0 + j].y;
        wy[j][q] = exp2f(dy * dy * scale);
    }
    if (threadIdx.x < NC) sy[threadIdx.x] = Yb[n0 + threadIdx.x];
    __syncthreads();

    // --- inner loop: 2x2 cell tile per thread, 16 VALU / 4 entries ---
    const int ixp = threadIdx.x & 31;  // ix pair -> ix = 2*ixp
    const int iyp = threadIdx.x >> 5;  // iy pair -> iy-local = 2*iyp
    float c00 = 0, c01 = 0, c02 = 0;   // (iyA, ixA)
    float c10 = 0, c11 = 0, c12 = 0;   // (iyA, ixB)
    float c20 = 0, c21 = 0, c22 = 0;   // (iyB, ixA)
    float c30 = 0, c31 = 0, c32 = 0;   // (iyB, ixB)

#pragma unroll 4
    for (int n = 0; n < NC; ++n) {
        const float2 wxv = *(const float2*)&wx[n][ixp * 2];  // 2-way aliased b64: free
        const float2 wyv = *(const float2*)&wy[n][iyp * 2];  // broadcast-heavy: free
        const float2 yv  = sy[n];                            // full broadcast
        const float pA0 = wyv.x * yv.x, pA1 = wyv.x * yv.y;
        const float pB0 = wyv.y * yv.x, pB1 = wyv.y * yv.y;
        c00 = fmaf(wxv.x, wyv.x, c00); c01 = fmaf(wxv.x, pA0, c01); c02 = fmaf(wxv.x, pA1, c02);
        c10 = fmaf(wxv.y, wyv.x, c10); c11 = fmaf(wxv.y, pA0, c11); c12 = fmaf(wxv.y, pA1, c12);
        c20 = fmaf(wxv.x, wyv.y, c20); c21 = fmaf(wxv.x, pB0, c21); c22 = fmaf(wxv.x, pB1, c22);
        c30 = fmaf(wxv.y, wyv.y, c30); c31 = fmaf(wxv.y, pB0, c31); c32 = fmaf(wxv.y, pB1, c32);
    }

    // --- write partials: ws[b][nc][c][g], float2 stores (coalesced pairs) ---
    float* base = ws + (((size_t)(b * NSPLIT + nc)) * 3) * NG;
    const int g0 = (iy0 + 2 * iyp) * 64 + 2 * ixp;   // even -> 8B aligned
    *(float2*)&base[g0]           = make_float2(c00, c10);
    *(float2*)&base[g0 + 64]      = make_float2(c20, c30);
    *(float2*)&base[NG + g0]      = make_float2(c01, c11);
    *(float2*)&base[NG + g0 + 64] = make_float2(c21, c31);
    *(float2*)&base[2*NG + g0]      = make_float2(c02, c12);
    *(float2*)&base[2*NG + g0 + 64] = make_float2(c22, c32);
}

__global__ __launch_bounds__(256)
void ee_reduce(const float* __restrict__ ws, float* __restrict__ out) {
    const int t = blockIdx.x * 256 + threadIdx.x;   // 65536 = 16*4096
    const int b = t >> 12, g = t & 4095;
    const float* base = ws + (size_t)b * NSPLIT * 3 * NG;
    float a0 = 0, a1 = 0, a2 = 0;
#pragma unroll
    for (int nc = 0; nc < NSPLIT; ++nc) {
        const float* p = base + nc * 3 * NG;
        a0 += p[g];
        a1 += p[NG + g];
        a2 += p[2 * NG + g];
    }
    const float inv = 1.0f / a0;   // a0 > 0 (sum of exps)
    float* ob = out + (size_t)b * 3 * NG;
    ob[g]          = a0;
    ob[NG + g]     = a1 * inv;
    ob[2 * NG + g] = a2 * inv;
}

extern "C" void kernel_launch(void* const* d_in, const int* in_sizes, int n_in,
                              void* d_out, int out_size, void* d_ws, size_t ws_size,
                              hipStream_t stream) {
    const float* X    = (const float*)d_in[0];   // (16,1024,2) fp32
    const float* Y    = (const float*)d_in[1];   // (16,1024,2) fp32
    const float* logl = (const float*)d_in[2];   // scalar fp32
    float* out = (float*)d_out;                  // (16,3,64,64) fp32
    float* ws  = (float*)d_ws;                   // needs 16*16*3*4096*4 = 12.6 MB

    ee_partial<<<dim3(NB * GQ * NSPLIT), dim3(256), 0, stream>>>(X, Y, logl, ws);
    ee_reduce <<<dim3(NB * NG / 256),    dim3(256), 0, stream>>>(ws, out);
}

// Round 3
// 72.541 us; speedup vs baseline: 1.2400x; 1.0050x over previous
//
#include <hip/hip_runtime.h>
#include <hip/hip_bf16.h>
#include <math.h>

// EquivEncoder: B=16, N_CTX=1024, 64x64 grid, fp32.
// out[b,c,iy,ix]: c0 = dens = sum_n w, c1 = (sum_n w*y0)/dens, c2 = (sum_n w*y1)/dens
// w = exp2(s*dx^2)*exp2(s*dy^2), s = -0.5*log2(e)*exp(-2*logl)
//
// R3 design (R2 was LDS-BW bound at 6 B/entry):
//  - 4ix x 4iy register tile per thread -> 2.5 B LDS per Gram entry, 3.5 VALU/entry
//  - one 256-thread block covers the full 64x64 grid; nsplit=16 over N_CTX
//    -> 256 blocks = 1 block/CU; 48 indep FMA chains/thread hide latency at 1 wave/SIMD
//  - partials (16 x 16 x 3 x 4096 fp32 = 12.6 MB) -> d_ws; reduce kernel sums + divides

#define NB     16
#define NCTX   1024
#define NG     4096
#define NSPLIT 16
#define NC     64      // NCTX / NSPLIT

__global__ __launch_bounds__(256, 1)
void ee_partial(const float* __restrict__ X,
                const float* __restrict__ Y,
                const float* __restrict__ log_l_scale,
                float* __restrict__ ws) {
    const int b  = blockIdx.x >> 4;
    const int nc = blockIdx.x & 15;
    const int n0 = nc * NC;

    const float step  = 20.0f / 63.0f;
    const float scale = -0.72134752044448170f * expf(-2.0f * log_l_scale[0]);

    __shared__ float  wx[NC][64];    // 16 KB  exp2(s*dx^2) for (n, ix)
    __shared__ float  wy[NC][64];    // 16 KB  exp2(s*dy^2) for (n, iy)
    __shared__ float2 sy[NC];        // 512 B  (y0, y1)

    const float2* Xb = (const float2*)(X + (size_t)b * NCTX * 2);
    const float2* Yb = (const float2*)(Y + (size_t)b * NCTX * 2);

    // --- tables: 16 iters/thread, one 8B global load + 2 exps each ---
    for (int idx = threadIdx.x; idx < NC * 64; idx += 256) {
        const int j = idx >> 6, i = idx & 63;
        const float2 xv = Xb[n0 + j];
        const float dx = (-10.0f + step * (float)i) - xv.x;
        const float dy = ( 10.0f - step * (float)i) - xv.y;
        wx[j][i] = exp2f(dx * dx * scale);
        wy[j][i] = exp2f(dy * dy * scale);
    }
    if (threadIdx.x < NC) sy[threadIdx.x] = Yb[n0 + threadIdx.x];
    __syncthreads();

    // --- 4x4 cell tile per thread: ix0 = 4*tx, iy = 4*ty + s ---
    const int tx = threadIdx.x & 15;
    const int ty = threadIdx.x >> 4;
    const int ix0 = tx * 4;
    const int iy0 = ty * 4;

    float4 ad[4] = {{0,0,0,0},{0,0,0,0},{0,0,0,0},{0,0,0,0}};  // dens
    float4 a1[4] = {{0,0,0,0},{0,0,0,0},{0,0,0,0},{0,0,0,0}};  // sum w*y0
    float4 a2[4] = {{0,0,0,0},{0,0,0,0},{0,0,0,0},{0,0,0,0}};  // sum w*y1

#pragma unroll 4
    for (int n = 0; n < NC; ++n) {
        const float4 wxv = *(const float4*)&wx[n][ix0];  // contiguous row b128
        const float4 wyv = *(const float4*)&wy[n][iy0];  // 4-addr broadcast b128
        const float2 yv  = sy[n];                        // full broadcast
        const float wys[4] = {wyv.x, wyv.y, wyv.z, wyv.w};
#pragma unroll
        for (int s = 0; s < 4; ++s) {
            const float w  = wys[s];
            const float q1 = w * yv.x;
            const float q2 = w * yv.y;
            ad[s].x = fmaf(wxv.x, w, ad[s].x);  ad[s].y = fmaf(wxv.y, w, ad[s].y);
            ad[s].z = fmaf(wxv.z, w, ad[s].z);  ad[s].w = fmaf(wxv.w, w, ad[s].w);
            a1[s].x = fmaf(wxv.x, q1, a1[s].x); a1[s].y = fmaf(wxv.y, q1, a1[s].y);
            a1[s].z = fmaf(wxv.z, q1, a1[s].z); a1[s].w = fmaf(wxv.w, q1, a1[s].w);
            a2[s].x = fmaf(wxv.x, q2, a2[s].x); a2[s].y = fmaf(wxv.y, q2, a2[s].y);
            a2[s].z = fmaf(wxv.z, q2, a2[s].z); a2[s].w = fmaf(wxv.w, q2, a2[s].w);
        }
    }

    // --- partials: ws[b][nc][c][g], float4 stores ---
    float* base = ws + ((size_t)(b * NSPLIT + nc)) * 3 * NG;
#pragma unroll
    for (int s = 0; s < 4; ++s) {
        const int g = (iy0 + s) * 64 + ix0;
        *(float4*)&base[g]          = ad[s];
        *(float4*)&base[NG + g]     = a1[s];
        *(float4*)&base[2*NG + g]   = a2[s];
    }
}

__global__ __launch_bounds__(256)
void ee_reduce(const float* __restrict__ ws, float* __restrict__ out) {
    const int t = blockIdx.x * 256 + threadIdx.x;   // 65536 = 16*4096
    const int b = t >> 12, g = t & 4095;
    const float* base = ws + (size_t)b * NSPLIT * 3 * NG;
    float a0 = 0, a1 = 0, a2 = 0;
#pragma unroll
    for (int nc = 0; nc < NSPLIT; ++nc) {
        const float* p = base + nc * 3 * NG;
        a0 += p[g];
        a1 += p[NG + g];
        a2 += p[2 * NG + g];
    }
    const float inv = 1.0f / a0;   // a0 > 0 (sum of exps)
    float* ob = out + (size_t)b * 3 * NG;
    ob[g]          = a0;
    ob[NG + g]     = a1 * inv;
    ob[2 * NG + g] = a2 * inv;
}

extern "C" void kernel_launch(void* const* d_in, const int* in_sizes, int n_in,
                              void* d_out, int out_size, void* d_ws, size_t ws_size,
                              hipStream_t stream) {
    const float* X    = (const float*)d_in[0];   // (16,1024,2) fp32
    const float* Y    = (const float*)d_in[1];   // (16,1024,2) fp32
    const float* logl = (const float*)d_in[2];   // scalar fp32
    float* out = (float*)d_out;                  // (16,3,64,64) fp32
    float* ws  = (float*)d_ws;                   // 16*16*3*4096*4 = 12.6 MB

    ee_partial<<<dim3(NB * NSPLIT), dim3(256), 0, stream>>>(X, Y, logl, ws);
    ee_reduce <<<dim3(NB * NG / 256), dim3(256), 0, stream>>>(ws, out);
}